// Round 9
// baseline (255.400 us; speedup 1.0000x reference)
//
#include <hip/hip_runtime.h>
#include <hip/hip_bf16.h>

// Fused causal MHA. B=2, S=2048, E=1024, H=16, D=64. fp32 in/out.
// R9: attention occupancy push — unpaired heavy-first q-tiles (1024 blocks),
// LDS cut to exactly 40KB (Ps XOR-rotated, no pad) -> 4 blocks/CU, and the
// softmax denominator computed by an extra ones-MFMA instead of VALU adds.

typedef __bf16 bf16;
typedef bf16 bf16x4 __attribute__((ext_vector_type(4)));
typedef bf16 bf16x8 __attribute__((ext_vector_type(8)));
typedef float f32x4 __attribute__((ext_vector_type(4)));

constexpr int BSZ = 2, SEQ = 2048, EMBED = 1024, HEADS = 16, HDIM = 64;
constexpr int MTOT = BSZ * SEQ;       // 4096
constexpr int KDIM = EMBED;           // 1024
constexpr float QSCALE = 0.125f * 1.4426950408889634f;  // 1/sqrt(64) * log2(e)

constexpr size_t XSZ = (size_t)MTOT * EMBED;   // 4M elems (1<<22)
constexpr size_t WSZ = (size_t)EMBED * EMBED;  // 1M elems (1<<20)

// async global->LDS, 16B/lane; lds dest wave-uniform base + lane*16
__device__ inline void load_lds16(const bf16* g, bf16* l) {
    __builtin_amdgcn_global_load_lds(
        (const __attribute__((address_space(1))) unsigned int*)g,
        (__attribute__((address_space(3))) unsigned int*)l, 16, 0, 0);
}

// ---------------------------------------------------------------------------
// fp32 -> bf16 conversion: 3 X tensors (4M each) + 4 W tensors (1M each).
// ---------------------------------------------------------------------------
__global__ __launch_bounds__(256) void cvt_bf16(
    const float* __restrict__ x0, const float* __restrict__ x1, const float* __restrict__ x2,
    const float* __restrict__ w0, const float* __restrict__ w1,
    const float* __restrict__ w2, const float* __restrict__ w3,
    bf16* __restrict__ dst) {
    const size_t i = ((size_t)blockIdx.x * blockDim.x + threadIdx.x) * 8;
    const float* src;
    size_t off;
    if (i < 3 * XSZ) {
        const int s = (int)(i >> 22);
        src = s == 0 ? x0 : (s == 1 ? x1 : x2);
        off = i & (XSZ - 1);
    } else {
        const size_t j = i - 3 * XSZ;
        const int s = (int)(j >> 20);
        src = s == 0 ? w0 : (s == 1 ? w1 : (s == 2 ? w2 : w3));
        off = j & (WSZ - 1);
    }
    float4 a = *(const float4*)(src + off);
    float4 b = *(const float4*)(src + off + 4);
    bf16x8 v = {(bf16)a.x, (bf16)a.y, (bf16)a.z, (bf16)a.w,
                (bf16)b.x, (bf16)b.y, (bf16)b.z, (bf16)b.w};
    *(bf16x8*)(dst + i) = v;
}

// ---------------------------------------------------------------------------
// m97-style GEMM inner loop with XOR row-rotation swizzle (R8, verified:
// conflicts 9.4M -> off the radar).
// ---------------------------------------------------------------------------
struct MMCtx {
    int wave, lane, quad, l16, wm, wn, lrow, lcol;
};
__device__ inline MMCtx mm_ctx() {
    MMCtx c;
    const int tid = threadIdx.x;
    c.wave = tid >> 6; c.lane = tid & 63;
    c.quad = c.lane >> 4; c.l16 = c.lane & 15;
    c.wm = (c.wave & 1) * 64; c.wn = (c.wave >> 1) * 64;
    c.lrow = c.lane >> 3; c.lcol = (c.lane & 7) * 8;
    return c;
}

// SWAP=false: acc row=A-row(quad*4+r), col=W-row(l16). SWAP=true: transposed.
template <bool SWAP>
__device__ inline void mm_loop(const bf16* __restrict__ A, const bf16* __restrict__ W,
                               int rowA0, int rowB0, const MMCtx& c,
                               bf16 (*As)[64], bf16 (*Bs)[64], f32x4 acc[4][4]) {
    for (int k0 = 0; k0 < KDIM; k0 += 64) {
        for (int i = 0; i < 4; ++i) {
            const int r0 = (c.wave * 4 + i) * 8;
            const int row = r0 + c.lrow;
            const int gcol = (c.lcol - 8 * row) & 63;
            load_lds16(&A[(size_t)(rowA0 + row) * KDIM + k0 + gcol], &As[r0][0]);
            load_lds16(&W[(size_t)(rowB0 + row) * KDIM + k0 + gcol], &Bs[r0][0]);
        }
        __syncthreads();
        for (int ks = 0; ks < 64; ks += 32) {
            bf16x8 af[4], bfr[4];
            for (int mt = 0; mt < 4; ++mt) {
                const int row = c.wm + mt * 16 + c.l16;
                af[mt] = *(const bf16x8*)&As[row][(ks + c.quad * 8 + 8 * row) & 63];
            }
            for (int nt = 0; nt < 4; ++nt) {
                const int row = c.wn + nt * 16 + c.l16;
                bfr[nt] = *(const bf16x8*)&Bs[row][(ks + c.quad * 8 + 8 * row) & 63];
            }
            for (int mt = 0; mt < 4; ++mt)
                for (int nt = 0; nt < 4; ++nt)
                    acc[mt][nt] = SWAP
                        ? __builtin_amdgcn_mfma_f32_16x16x32_bf16(bfr[nt], af[mt], acc[mt][nt], 0, 0, 0)
                        : __builtin_amdgcn_mfma_f32_16x16x32_bf16(af[mt], bfr[nt], acc[mt][nt], 0, 0, 0);
        }
        __syncthreads();
    }
}

// ---------------------------------------------------------------------------
// QKV projection. z=0: Q scaled -> [B,H,S,D]; z=1: K -> [B,H,S,D];
// z=2: V -> [B,H,D,S]. Packed bf16x4 stores.
// ---------------------------------------------------------------------------
__global__ __launch_bounds__(256) void gemm_qkv(
    const bf16* __restrict__ Xq, const bf16* __restrict__ Xk, const bf16* __restrict__ Xv,
    const bf16* __restrict__ Wq, const bf16* __restrict__ Wk, const bf16* __restrict__ Wv,
    const float* __restrict__ bq, const float* __restrict__ bk, const float* __restrict__ bv,
    bf16* __restrict__ Qp, bf16* __restrict__ Kp, bf16* __restrict__ Vtp) {
    __shared__ bf16 As[128][64];
    __shared__ bf16 Bs[128][64];

    const int z = blockIdx.z;
    const bf16* A     = z == 0 ? Xq : (z == 1 ? Xk : Xv);
    const bf16* W     = z == 0 ? Wq : (z == 1 ? Wk : Wv);
    const float* bias = z == 0 ? bq : (z == 1 ? bk : bv);
    const float scale = z == 0 ? QSCALE : 1.0f;

    const MMCtx c = mm_ctx();
    const int rowA0 = blockIdx.x * 128;
    const int rowB0 = blockIdx.y * 128;
    f32x4 acc[4][4] = {};

    if (z < 2) {
        mm_loop<true>(A, W, rowA0, rowB0, c, As, Bs, acc);
        bf16* dst = z == 0 ? Qp : Kp;
        for (int mt = 0; mt < 4; ++mt) {
            const int xrow = rowA0 + c.wm + mt * 16 + c.l16;
            const int b = xrow >> 11, s = xrow & (SEQ - 1);
            for (int nt = 0; nt < 4; ++nt) {
                const int f0 = rowB0 + c.wn + nt * 16 + c.quad * 4;
                const float4 bb = *(const float4*)&bias[f0];
                const int h = f0 >> 6, d0 = f0 & (HDIM - 1);
                f32x4 a = acc[mt][nt];
                bf16x4 pk = {(bf16)((a[0] + bb.x) * scale), (bf16)((a[1] + bb.y) * scale),
                             (bf16)((a[2] + bb.z) * scale), (bf16)((a[3] + bb.w) * scale)};
                *(bf16x4*)&dst[(((size_t)(b * HEADS + h)) * SEQ + s) * HDIM + d0] = pk;
            }
        }
    } else {
        mm_loop<false>(A, W, rowA0, rowB0, c, As, Bs, acc);
        for (int nt = 0; nt < 4; ++nt) {
            const int f = rowB0 + c.wn + nt * 16 + c.l16;
            const float bb = bias[f];
            const int h = f >> 6, d = f & (HDIM - 1);
            for (int mt = 0; mt < 4; ++mt) {
                const int xrow0 = rowA0 + c.wm + mt * 16 + c.quad * 4;
                const int b = xrow0 >> 11, s0 = xrow0 & (SEQ - 1);
                f32x4 a = acc[mt][nt];
                bf16x4 pk = {(bf16)(a[0] + bb), (bf16)(a[1] + bb),
                             (bf16)(a[2] + bb), (bf16)(a[3] + bb)};
                *(bf16x4*)&Vtp[(((size_t)(b * HEADS + h)) * HDIM + d) * SEQ + s0] = pk;
            }
        }
    }
}

// ---------------------------------------------------------------------------
// Output projection: 128x64 tiles -> grid (32,16) = 512 blocks (2/CU).
// ---------------------------------------------------------------------------
__global__ __launch_bounds__(256) void gemm_out(const bf16* __restrict__ A,
                                                const bf16* __restrict__ W,
                                                const float* __restrict__ bias,
                                                float* __restrict__ C) {
    __shared__ bf16 As[128][64];
    __shared__ bf16 Bs[64][64];

    const int tid = threadIdx.x;
    const int wave = tid >> 6, lane = tid & 63;
    const int quad = lane >> 4, l16 = lane & 15;
    const int wm = (wave & 1) * 64, wn = (wave >> 1) * 32;
    const int lrow = lane >> 3, lcol = (lane & 7) * 8;
    const int rowA0 = blockIdx.x * 128;   // M rows
    const int rowB0 = blockIdx.y * 64;    // N features

    f32x4 acc[4][2] = {};
    for (int k0 = 0; k0 < KDIM; k0 += 64) {
        for (int i = 0; i < 4; ++i) {
            const int r0 = (wave * 4 + i) * 8;
            const int row = r0 + lrow;
            const int gcol = (lcol - 8 * row) & 63;
            load_lds16(&A[(size_t)(rowA0 + row) * KDIM + k0 + gcol], &As[r0][0]);
        }
        for (int i = 0; i < 2; ++i) {
            const int r0 = (wave * 2 + i) * 8;
            const int row = r0 + lrow;
            const int gcol = (lcol - 8 * row) & 63;
            load_lds16(&W[(size_t)(rowB0 + row) * KDIM + k0 + gcol], &Bs[r0][0]);
        }
        __syncthreads();
        for (int ks = 0; ks < 64; ks += 32) {
            bf16x8 af[4], bfr[2];
            for (int mt = 0; mt < 4; ++mt) {
                const int row = wm + mt * 16 + l16;
                af[mt] = *(const bf16x8*)&As[row][(ks + quad * 8 + 8 * row) & 63];
            }
            for (int nt = 0; nt < 2; ++nt) {
                const int row = wn + nt * 16 + l16;
                bfr[nt] = *(const bf16x8*)&Bs[row][(ks + quad * 8 + 8 * row) & 63];
            }
            for (int mt = 0; mt < 4; ++mt)
                for (int nt = 0; nt < 2; ++nt)
                    acc[mt][nt] = __builtin_amdgcn_mfma_f32_16x16x32_bf16(
                        bfr[nt], af[mt], acc[mt][nt], 0, 0, 0);   // SWAP orientation
        }
        __syncthreads();
    }

    for (int mt = 0; mt < 4; ++mt) {
        const int row = rowA0 + wm + mt * 16 + l16;
        for (int nt = 0; nt < 2; ++nt) {
            const int f0 = rowB0 + wn + nt * 16 + quad * 4;
            const float4 bb = *(const float4*)&bias[f0];
            f32x4 a = acc[mt][nt];
            float4 v = {a[0] + bb.x, a[1] + bb.y, a[2] + bb.z, a[3] + bb.w};
            *(float4*)&C[(size_t)row * EMBED + f0] = v;
        }
    }
}

// ---------------------------------------------------------------------------
// Flash attention, causal. R9: grid 1024 (= 32 qt x 32 bh), heavy-first
// dispatch, XCD remap (XCD a owns heads [4a,4a+4)); 40960B LDS -> 4
// blocks/CU; denominator via ones-MFMA (no VALU adds, no shuffles).
// ---------------------------------------------------------------------------
__global__ __launch_bounds__(256, 4) void attn_flash(const bf16* __restrict__ Q,
                                                     const bf16* __restrict__ K,
                                                     const bf16* __restrict__ Vt,
                                                     bf16* __restrict__ O) {
    const int l = blockIdx.x;                    // 0..1023
    const int a = l & 7, s = l >> 3;             // XCD, slot in XCD
    const int bh = 4 * a + (s >> 5);             // 4 heads per XCD
    const int qt = 31 - (s & 31);                // heavy tiles dispatch first
    const int wave = threadIdx.x >> 6, lane = threadIdx.x & 63;
    const int quad = lane >> 4, l16 = lane & 15;
    const int qw = qt * 64 + wave * 16;          // this wave's 16 q-rows
    const int nk = qt + 1;                       // 64-key iterations

    const bf16* Qh = Q + (size_t)bh * SEQ * HDIM;
    const bf16* Kh = K + (size_t)bh * SEQ * HDIM;
    const bf16* Vh = Vt + (size_t)bh * HDIM * SEQ;

    __shared__ bf16 Ks[2][64][64];   // [buf][key][d], rows rotated by 8*row
    __shared__ bf16 Vs[2][64][64];   // [buf][d][key], same rotation
    __shared__ bf16 Ps[4][16][64];   // per-wave P^T [q][key], rotated by 8*q

    const int srow = wave * 8 + (lane >> 3);
    const int scolL = (lane & 7) * 8;
    const int b = bh >> 4, h = bh & 15;

    auto stage = [&](int buf, int k0) {
        for (int cc = 0; cc < 2; ++cc) {
            const int row = srow + cc * 32;
            const int gcol = (scolL - 8 * row) & 63;
            load_lds16(&Kh[(size_t)(k0 + row) * HDIM + gcol], &Ks[buf][wave * 8 + cc * 32][0]);
            load_lds16(&Vh[(size_t)row * SEQ + k0 + gcol], &Vs[buf][wave * 8 + cc * 32][0]);
        }
    };

    bf16x8 qf[2];                                // B-frag: B[n=q=l16][k=d]
    for (int ks = 0; ks < 2; ++ks)
        qf[ks] = *(const bf16x8*)&Qh[(size_t)(qw + l16) * HDIM + ks * 32 + quad * 8];

    bf16x8 ones;
    for (int i = 0; i < 8; ++i) ones[i] = (bf16)1.0f;

    f32x4 ot[4] = {};                            // O^T: col=q=l16, row=d=quad*4+r
    f32x4 lacc = {};                             // ones-MFMA denominator

    stage(0, 0);
#pragma unroll 1
    for (int it = 0; it < nk; ++it) {
        const int k0 = it * 64;
        const int buf = it & 1;
        __syncthreads();                         // buf's DMA landed; prior reads done
        if (it + 1 < nk) stage(buf ^ 1, k0 + 64);

        if (k0 < qw + 16) {                      // wave-uniform causal skip
            // S^T = K Q^T : col=q=l16, row=key=mt*16+quad*4+r
            f32x4 st[4] = {};
            for (int mt = 0; mt < 4; ++mt) {
                const int krow = mt * 16 + l16;
                for (int ks = 0; ks < 2; ++ks) {
                    const int colL = (ks * 32 + 8 * (quad + krow)) & 63;
                    bf16x8 kf = *(const bf16x8*)&Ks[buf][krow][colL];
                    st[mt] = __builtin_amdgcn_mfma_f32_16x16x32_bf16(kf, qf[ks], st[mt], 0, 0, 0);
                }
            }
            if (k0 + 63 >= qw) {                 // diagonal-touching tile
                const int q = qw + l16;
                for (int mt = 0; mt < 4; ++mt) {
                    const int key = k0 + mt * 16 + quad * 4;
                    for (int r = 0; r < 4; ++r)
                        if (key + r > q) st[mt][r] = -__builtin_inff();
                }
            }
            // P = exp2(S^T), pack to rotated Ps
            for (int mt = 0; mt < 4; ++mt) {
                f32x4 p;
                for (int r = 0; r < 4; ++r) p[r] = exp2f(st[mt][r]);
                bf16x4 pk = {(bf16)p[0], (bf16)p[1], (bf16)p[2], (bf16)p[3]};
                *(bf16x4*)&Ps[wave][l16][(mt * 16 + quad * 4 + 8 * l16) & 63] = pk;
            }
            // O^T += Vt P^T ; lacc += ones P^T (softmax denominator)
            for (int half = 0; half < 2; ++half) {
                bf16x8 pf = *(const bf16x8*)&Ps[wave][l16][(half * 32 + quad * 8 + 8 * l16) & 63];
                lacc = __builtin_amdgcn_mfma_f32_16x16x32_bf16(ones, pf, lacc, 0, 0, 0);
                for (int dt = 0; dt < 4; ++dt) {
                    const int drow = dt * 16 + l16;
                    const int colL = (half * 32 + 8 * (quad + drow)) & 63;
                    bf16x8 vf = *(const bf16x8*)&Vs[buf][drow][colL];
                    ot[dt] = __builtin_amdgcn_mfma_f32_16x16x32_bf16(vf, pf, ot[dt], 0, 0, 0);
                }
            }
        }
    }

    const float inv = 1.f / lacc[0];             // all 4 regs equal = sum over keys
    const int sq = qw + l16;
    for (int dt = 0; dt < 4; ++dt) {
        bf16x4 pk = {(bf16)(ot[dt][0] * inv), (bf16)(ot[dt][1] * inv),
                     (bf16)(ot[dt][2] * inv), (bf16)(ot[dt][3] * inv)};
        *(bf16x4*)&O[((size_t)(b * SEQ + sq)) * EMBED + h * HDIM + dt * 16 + quad * 4] = pk;
    }
}

// ---------------------------------------------------------------------------
extern "C" void kernel_launch(void* const* d_in, const int* in_sizes, int n_in,
                              void* d_out, int out_size, void* d_ws, size_t ws_size,
                              hipStream_t stream) {
    const float* q_in = (const float*)d_in[0];
    const float* k_in = (const float*)d_in[1];
    const float* v_in = (const float*)d_in[2];
    // d_in[3] = causal mask — applied analytically
    const float* Wq = (const float*)d_in[4];
    const float* bq = (const float*)d_in[5];
    const float* Wk = (const float*)d_in[6];
    const float* bk = (const float*)d_in[7];
    const float* Wv = (const float*)d_in[8];
    const float* bv = (const float*)d_in[9];
    const float* Wo = (const float*)d_in[10];
    const float* bo = (const float*)d_in[11];

    bf16* ws = (bf16*)d_ws;
    // [0,12M): Xq,Xk,Xv  [12M,16M): Wq,Wk,Wv,Wo  [16M,28M): Qp,Kp,Vtp
    // AO aliases Xq (free after gemm_qkv).
    bf16* Xb  = ws;
    bf16* Wb  = ws + 3 * XSZ;
    bf16* Qp  = ws + 3 * XSZ + 4 * WSZ;
    bf16* Kp  = Qp + XSZ;
    bf16* Vtp = Kp + XSZ;
    bf16* AO  = ws;

    const size_t total = 3 * XSZ + 4 * WSZ;   // 16M elems
    dim3 bb(256);
    cvt_bf16<<<dim3((unsigned)(total / 8 / 256)), bb, 0, stream>>>(
        q_in, k_in, v_in, Wq, Wk, Wv, Wo, ws);
    gemm_qkv<<<dim3(MTOT / 128, EMBED / 128, 3), bb, 0, stream>>>(
        Xb, Xb + XSZ, Xb + 2 * XSZ, Wb, Wb + WSZ, Wb + 2 * WSZ,
        bq, bk, bv, Qp, Kp, Vtp);
    attn_flash<<<dim3(1024), bb, 0, stream>>>(Qp, Kp, Vtp, AO);
    gemm_out<<<dim3(MTOT / 128, EMBED / 64), bb, 0, stream>>>(
        AO, Wb + 3 * WSZ, bo, (float*)d_out);
}

// Round 10
// 241.786 us; speedup vs baseline: 1.0563x; 1.0563x over previous
//
#include <hip/hip_runtime.h>
#include <hip/hip_bf16.h>

// Fused causal MHA. B=2, S=2048, E=1024, H=16, D=64. fp32 in/out.
// R10: attention = R8's paired/balanced structure + R9's ones-MFMA
// denominator + 128-key tiles (half the barriers per phase).
// R9 lesson: all-resident grids need equal work per block — pairing, not
// occupancy, is what sets duty cycle here.

typedef __bf16 bf16;
typedef bf16 bf16x4 __attribute__((ext_vector_type(4)));
typedef bf16 bf16x8 __attribute__((ext_vector_type(8)));
typedef float f32x4 __attribute__((ext_vector_type(4)));

constexpr int BSZ = 2, SEQ = 2048, EMBED = 1024, HEADS = 16, HDIM = 64;
constexpr int MTOT = BSZ * SEQ;       // 4096
constexpr int KDIM = EMBED;           // 1024
constexpr float QSCALE = 0.125f * 1.4426950408889634f;  // 1/sqrt(64) * log2(e)

constexpr size_t XSZ = (size_t)MTOT * EMBED;   // 4M elems (1<<22)
constexpr size_t WSZ = (size_t)EMBED * EMBED;  // 1M elems (1<<20)

// async global->LDS, 16B/lane; lds dest wave-uniform base + lane*16
__device__ inline void load_lds16(const bf16* g, bf16* l) {
    __builtin_amdgcn_global_load_lds(
        (const __attribute__((address_space(1))) unsigned int*)g,
        (__attribute__((address_space(3))) unsigned int*)l, 16, 0, 0);
}

// ---------------------------------------------------------------------------
// fp32 -> bf16 conversion: 3 X tensors (4M each) + 4 W tensors (1M each).
// ---------------------------------------------------------------------------
__global__ __launch_bounds__(256) void cvt_bf16(
    const float* __restrict__ x0, const float* __restrict__ x1, const float* __restrict__ x2,
    const float* __restrict__ w0, const float* __restrict__ w1,
    const float* __restrict__ w2, const float* __restrict__ w3,
    bf16* __restrict__ dst) {
    const size_t i = ((size_t)blockIdx.x * blockDim.x + threadIdx.x) * 8;
    const float* src;
    size_t off;
    if (i < 3 * XSZ) {
        const int s = (int)(i >> 22);
        src = s == 0 ? x0 : (s == 1 ? x1 : x2);
        off = i & (XSZ - 1);
    } else {
        const size_t j = i - 3 * XSZ;
        const int s = (int)(j >> 20);
        src = s == 0 ? w0 : (s == 1 ? w1 : (s == 2 ? w2 : w3));
        off = j & (WSZ - 1);
    }
    float4 a = *(const float4*)(src + off);
    float4 b = *(const float4*)(src + off + 4);
    bf16x8 v = {(bf16)a.x, (bf16)a.y, (bf16)a.z, (bf16)a.w,
                (bf16)b.x, (bf16)b.y, (bf16)b.z, (bf16)b.w};
    *(bf16x8*)(dst + i) = v;
}

// ---------------------------------------------------------------------------
// m97-style GEMM inner loop with XOR row-rotation swizzle (verified R8).
// ---------------------------------------------------------------------------
struct MMCtx {
    int wave, lane, quad, l16, wm, wn, lrow, lcol;
};
__device__ inline MMCtx mm_ctx() {
    MMCtx c;
    const int tid = threadIdx.x;
    c.wave = tid >> 6; c.lane = tid & 63;
    c.quad = c.lane >> 4; c.l16 = c.lane & 15;
    c.wm = (c.wave & 1) * 64; c.wn = (c.wave >> 1) * 64;
    c.lrow = c.lane >> 3; c.lcol = (c.lane & 7) * 8;
    return c;
}

template <bool SWAP>
__device__ inline void mm_loop(const bf16* __restrict__ A, const bf16* __restrict__ W,
                               int rowA0, int rowB0, const MMCtx& c,
                               bf16 (*As)[64], bf16 (*Bs)[64], f32x4 acc[4][4]) {
    for (int k0 = 0; k0 < KDIM; k0 += 64) {
        for (int i = 0; i < 4; ++i) {
            const int r0 = (c.wave * 4 + i) * 8;
            const int row = r0 + c.lrow;
            const int gcol = (c.lcol - 8 * row) & 63;
            load_lds16(&A[(size_t)(rowA0 + row) * KDIM + k0 + gcol], &As[r0][0]);
            load_lds16(&W[(size_t)(rowB0 + row) * KDIM + k0 + gcol], &Bs[r0][0]);
        }
        __syncthreads();
        for (int ks = 0; ks < 64; ks += 32) {
            bf16x8 af[4], bfr[4];
            for (int mt = 0; mt < 4; ++mt) {
                const int row = c.wm + mt * 16 + c.l16;
                af[mt] = *(const bf16x8*)&As[row][(ks + c.quad * 8 + 8 * row) & 63];
            }
            for (int nt = 0; nt < 4; ++nt) {
                const int row = c.wn + nt * 16 + c.l16;
                bfr[nt] = *(const bf16x8*)&Bs[row][(ks + c.quad * 8 + 8 * row) & 63];
            }
            for (int mt = 0; mt < 4; ++mt)
                for (int nt = 0; nt < 4; ++nt)
                    acc[mt][nt] = SWAP
                        ? __builtin_amdgcn_mfma_f32_16x16x32_bf16(bfr[nt], af[mt], acc[mt][nt], 0, 0, 0)
                        : __builtin_amdgcn_mfma_f32_16x16x32_bf16(af[mt], bfr[nt], acc[mt][nt], 0, 0, 0);
        }
        __syncthreads();
    }
}

// ---------------------------------------------------------------------------
// QKV projection. z=0: Q scaled -> [B,H,S,D]; z=1: K -> [B,H,S,D];
// z=2: V -> [B,H,D,S]. Packed bf16x4 stores.
// ---------------------------------------------------------------------------
__global__ __launch_bounds__(256) void gemm_qkv(
    const bf16* __restrict__ Xq, const bf16* __restrict__ Xk, const bf16* __restrict__ Xv,
    const bf16* __restrict__ Wq, const bf16* __restrict__ Wk, const bf16* __restrict__ Wv,
    const float* __restrict__ bq, const float* __restrict__ bk, const float* __restrict__ bv,
    bf16* __restrict__ Qp, bf16* __restrict__ Kp, bf16* __restrict__ Vtp) {
    __shared__ bf16 As[128][64];
    __shared__ bf16 Bs[128][64];

    const int z = blockIdx.z;
    const bf16* A     = z == 0 ? Xq : (z == 1 ? Xk : Xv);
    const bf16* W     = z == 0 ? Wq : (z == 1 ? Wk : Wv);
    const float* bias = z == 0 ? bq : (z == 1 ? bk : bv);
    const float scale = z == 0 ? QSCALE : 1.0f;

    const MMCtx c = mm_ctx();
    const int rowA0 = blockIdx.x * 128;
    const int rowB0 = blockIdx.y * 128;
    f32x4 acc[4][4] = {};

    if (z < 2) {
        mm_loop<true>(A, W, rowA0, rowB0, c, As, Bs, acc);
        bf16* dst = z == 0 ? Qp : Kp;
        for (int mt = 0; mt < 4; ++mt) {
            const int xrow = rowA0 + c.wm + mt * 16 + c.l16;
            const int b = xrow >> 11, s = xrow & (SEQ - 1);
            for (int nt = 0; nt < 4; ++nt) {
                const int f0 = rowB0 + c.wn + nt * 16 + c.quad * 4;
                const float4 bb = *(const float4*)&bias[f0];
                const int h = f0 >> 6, d0 = f0 & (HDIM - 1);
                f32x4 a = acc[mt][nt];
                bf16x4 pk = {(bf16)((a[0] + bb.x) * scale), (bf16)((a[1] + bb.y) * scale),
                             (bf16)((a[2] + bb.z) * scale), (bf16)((a[3] + bb.w) * scale)};
                *(bf16x4*)&dst[(((size_t)(b * HEADS + h)) * SEQ + s) * HDIM + d0] = pk;
            }
        }
    } else {
        mm_loop<false>(A, W, rowA0, rowB0, c, As, Bs, acc);
        for (int nt = 0; nt < 4; ++nt) {
            const int f = rowB0 + c.wn + nt * 16 + c.l16;
            const float bb = bias[f];
            const int h = f >> 6, d = f & (HDIM - 1);
            for (int mt = 0; mt < 4; ++mt) {
                const int xrow0 = rowA0 + c.wm + mt * 16 + c.quad * 4;
                const int b = xrow0 >> 11, s0 = xrow0 & (SEQ - 1);
                f32x4 a = acc[mt][nt];
                bf16x4 pk = {(bf16)(a[0] + bb), (bf16)(a[1] + bb),
                             (bf16)(a[2] + bb), (bf16)(a[3] + bb)};
                *(bf16x4*)&Vtp[(((size_t)(b * HEADS + h)) * HDIM + d) * SEQ + s0] = pk;
            }
        }
    }
}

// ---------------------------------------------------------------------------
// Output projection: 128x64 tiles -> grid (32,16) = 512 blocks (2/CU).
// ---------------------------------------------------------------------------
__global__ __launch_bounds__(256) void gemm_out(const bf16* __restrict__ A,
                                                const bf16* __restrict__ W,
                                                const float* __restrict__ bias,
                                                float* __restrict__ C) {
    __shared__ bf16 As[128][64];
    __shared__ bf16 Bs[64][64];

    const int tid = threadIdx.x;
    const int wave = tid >> 6, lane = tid & 63;
    const int quad = lane >> 4, l16 = lane & 15;
    const int wm = (wave & 1) * 64, wn = (wave >> 1) * 32;
    const int lrow = lane >> 3, lcol = (lane & 7) * 8;
    const int rowA0 = blockIdx.x * 128;   // M rows
    const int rowB0 = blockIdx.y * 64;    // N features

    f32x4 acc[4][2] = {};
    for (int k0 = 0; k0 < KDIM; k0 += 64) {
        for (int i = 0; i < 4; ++i) {
            const int r0 = (wave * 4 + i) * 8;
            const int row = r0 + lrow;
            const int gcol = (lcol - 8 * row) & 63;
            load_lds16(&A[(size_t)(rowA0 + row) * KDIM + k0 + gcol], &As[r0][0]);
        }
        for (int i = 0; i < 2; ++i) {
            const int r0 = (wave * 2 + i) * 8;
            const int row = r0 + lrow;
            const int gcol = (lcol - 8 * row) & 63;
            load_lds16(&W[(size_t)(rowB0 + row) * KDIM + k0 + gcol], &Bs[r0][0]);
        }
        __syncthreads();
        for (int ks = 0; ks < 64; ks += 32) {
            bf16x8 af[4], bfr[2];
            for (int mt = 0; mt < 4; ++mt) {
                const int row = wm + mt * 16 + l16;
                af[mt] = *(const bf16x8*)&As[row][(ks + quad * 8 + 8 * row) & 63];
            }
            for (int nt = 0; nt < 2; ++nt) {
                const int row = wn + nt * 16 + l16;
                bfr[nt] = *(const bf16x8*)&Bs[row][(ks + quad * 8 + 8 * row) & 63];
            }
            for (int mt = 0; mt < 4; ++mt)
                for (int nt = 0; nt < 2; ++nt)
                    acc[mt][nt] = __builtin_amdgcn_mfma_f32_16x16x32_bf16(
                        bfr[nt], af[mt], acc[mt][nt], 0, 0, 0);   // SWAP orientation
        }
        __syncthreads();
    }

    for (int mt = 0; mt < 4; ++mt) {
        const int row = rowA0 + wm + mt * 16 + l16;
        for (int nt = 0; nt < 2; ++nt) {
            const int f0 = rowB0 + wn + nt * 16 + quad * 4;
            const float4 bb = *(const float4*)&bias[f0];
            f32x4 a = acc[mt][nt];
            float4 v = {a[0] + bb.x, a[1] + bb.y, a[2] + bb.z, a[3] + bb.w};
            *(float4*)&C[(size_t)row * EMBED + f0] = v;
        }
    }
}

// ---------------------------------------------------------------------------
// Flash attention, causal. R10: 512 paired blocks (phases {31-p, p}; exact
// balance at 17-18 iters/block), XCD remap (XCD a owns heads [4a,4a+4)),
// 128-key tiles (half the barriers), double-buffered DMA staging,
// denominator via ones-MFMA. LDS 80KB -> 2 blocks/CU.
// ---------------------------------------------------------------------------
__global__ __launch_bounds__(256) void attn_flash(const bf16* __restrict__ Q,
                                                  const bf16* __restrict__ K,
                                                  const bf16* __restrict__ Vt,
                                                  bf16* __restrict__ O) {
    const int l = blockIdx.x;                    // 0..511
    const int a = l & 7, s = l >> 3;             // XCD, slot
    const int bh = 4 * a + (s >> 4);             // 4 heads per XCD
    const int pair = s & 15;                     // 0..15
    const int wave = threadIdx.x >> 6, lane = threadIdx.x & 63;
    const int quad = lane >> 4, l16 = lane & 15;

    const bf16* Qh = Q + (size_t)bh * SEQ * HDIM;
    const bf16* Kh = K + (size_t)bh * SEQ * HDIM;
    const bf16* Vh = Vt + (size_t)bh * HDIM * SEQ;

    __shared__ bf16 Ks[2][128][64];  // [buf][key][d], col rotated by 8*key mod 64
    __shared__ bf16 Vs[2][64][128];  // [buf][d][key], col rotated by 8*d mod 128
    __shared__ bf16 Ps[4][16][128];  // per-wave P^T [q][key], rotated by 8*q mod 128

    const int b = bh >> 4, h = bh & 15;

    // stage one 128-key tile (K: 128x64, V: 64x128), 4 DMA passes each
    auto stage = [&](int buf, int k0) {
        for (int cc = 0; cc < 4; ++cc) {
            const int krow = cc * 32 + wave * 8 + (lane >> 3);        // 0..127
            const int kg = (((lane & 7) * 8) - 8 * krow) & 63;
            load_lds16(&Kh[(size_t)(k0 + krow) * HDIM + kg], &Ks[buf][cc * 32 + wave * 8][0]);
            const int vrow = cc * 16 + wave * 4 + (lane >> 4);        // 0..63
            const int vg = (((lane & 15) * 8) - 8 * vrow) & 127;
            load_lds16(&Vh[(size_t)vrow * SEQ + k0 + vg], &Vs[buf][cc * 16 + wave * 4][0]);
        }
    };

    bf16x8 ones;
    for (int i = 0; i < 8; ++i) ones[i] = (bf16)1.0f;

#pragma unroll 1
    for (int phase = 0; phase < 2; ++phase) {
        const int qt = phase == 0 ? (31 - pair) : pair;
        const int qb = qt * 64;
        const int qw = qb + wave * 16;           // this wave's 16 q-rows
        const int nk = (qt + 2) >> 1;            // 128-key iterations

        bf16x8 qf[2];                            // B-frag: B[n=q=l16][k=d]
        for (int ks = 0; ks < 2; ++ks)
            qf[ks] = *(const bf16x8*)&Qh[(size_t)(qw + l16) * HDIM + ks * 32 + quad * 8];

        f32x4 ot[4] = {};                        // O^T: col=q=l16, row=d=quad*4+r
        f32x4 lacc = {};                         // ones-MFMA denominator

        stage(0, 0);
#pragma unroll 1
        for (int it = 0; it < nk; ++it) {
            const int k0 = it * 128;
            const int buf = it & 1;
            __syncthreads();                     // buf's DMA landed; prior reads done
            if (it + 1 < nk) stage(buf ^ 1, k0 + 128);

            if (k0 < qw + 16) {                  // wave-uniform causal skip
                // S^T = K Q^T : col=q=l16, row=key=mt*16+quad*4+r (mt 0..7)
                f32x4 st[8] = {};
                for (int mt = 0; mt < 8; ++mt) {
                    const int krow = mt * 16 + l16;
                    for (int ks = 0; ks < 2; ++ks) {
                        const int colL = (ks * 32 + 8 * (quad + krow)) & 63;
                        bf16x8 kf = *(const bf16x8*)&Ks[buf][krow][colL];
                        st[mt] = __builtin_amdgcn_mfma_f32_16x16x32_bf16(kf, qf[ks], st[mt], 0, 0, 0);
                    }
                }
                if (k0 + 127 >= qw) {            // diagonal-touching tile
                    const int q = qw + l16;
                    for (int mt = 0; mt < 8; ++mt) {
                        const int key = k0 + mt * 16 + quad * 4;
                        for (int r = 0; r < 4; ++r)
                            if (key + r > q) st[mt][r] = -__builtin_inff();
                    }
                }
                // P = exp2(S^T), pack to rotated Ps
                for (int mt = 0; mt < 8; ++mt) {
                    f32x4 p;
                    for (int r = 0; r < 4; ++r) p[r] = exp2f(st[mt][r]);
                    bf16x4 pk = {(bf16)p[0], (bf16)p[1], (bf16)p[2], (bf16)p[3]};
                    *(bf16x4*)&Ps[wave][l16][(mt * 16 + quad * 4 + 8 * l16) & 127] = pk;
                }
                // O^T += Vt P^T ; lacc += ones P^T (denominator)
                for (int c = 0; c < 4; ++c) {
                    bf16x8 pf = *(const bf16x8*)&Ps[wave][l16][(c * 32 + quad * 8 + 8 * l16) & 127];
                    lacc = __builtin_amdgcn_mfma_f32_16x16x32_bf16(ones, pf, lacc, 0, 0, 0);
                    for (int dt = 0; dt < 4; ++dt) {
                        const int drow = dt * 16 + l16;
                        const int colL = (c * 32 + quad * 8 + 8 * drow) & 127;
                        bf16x8 vf = *(const bf16x8*)&Vs[buf][drow][colL];
                        ot[dt] = __builtin_amdgcn_mfma_f32_16x16x32_bf16(vf, pf, ot[dt], 0, 0, 0);
                    }
                }
            }
        }
        __syncthreads();                         // reads done before next phase restages

        const float inv = 1.f / lacc[0];         // lacc rows all equal = sum_k P
        const int sq = qw + l16;
        for (int dt = 0; dt < 4; ++dt) {
            bf16x4 pk = {(bf16)(ot[dt][0] * inv), (bf16)(ot[dt][1] * inv),
                         (bf16)(ot[dt][2] * inv), (bf16)(ot[dt][3] * inv)};
            *(bf16x4*)&O[((size_t)(b * SEQ + sq)) * EMBED + h * HDIM + dt * 16 + quad * 4] = pk;
        }
    }
}

// ---------------------------------------------------------------------------
extern "C" void kernel_launch(void* const* d_in, const int* in_sizes, int n_in,
                              void* d_out, int out_size, void* d_ws, size_t ws_size,
                              hipStream_t stream) {
    const float* q_in = (const float*)d_in[0];
    const float* k_in = (const float*)d_in[1];
    const float* v_in = (const float*)d_in[2];
    // d_in[3] = causal mask — applied analytically
    const float* Wq = (const float*)d_in[4];
    const float* bq = (const float*)d_in[5];
    const float* Wk = (const float*)d_in[6];
    const float* bk = (const float*)d_in[7];
    const float* Wv = (const float*)d_in[8];
    const float* bv = (const float*)d_in[9];
    const float* Wo = (const float*)d_in[10];
    const float* bo = (const float*)d_in[11];

    bf16* ws = (bf16*)d_ws;
    // [0,12M): Xq,Xk,Xv  [12M,16M): Wq,Wk,Wv,Wo  [16M,28M): Qp,Kp,Vtp
    // AO aliases Xq (free after gemm_qkv).
    bf16* Xb  = ws;
    bf16* Wb  = ws + 3 * XSZ;
    bf16* Qp  = ws + 3 * XSZ + 4 * WSZ;
    bf16* Kp  = Qp + XSZ;
    bf16* Vtp = Kp + XSZ;
    bf16* AO  = ws;

    const size_t total = 3 * XSZ + 4 * WSZ;   // 16M elems
    dim3 bb(256);
    cvt_bf16<<<dim3((unsigned)(total / 8 / 256)), bb, 0, stream>>>(
        q_in, k_in, v_in, Wq, Wk, Wv, Wo, ws);
    gemm_qkv<<<dim3(MTOT / 128, EMBED / 128, 3), bb, 0, stream>>>(
        Xb, Xb + XSZ, Xb + 2 * XSZ, Wb, Wb + WSZ, Wb + 2 * WSZ,
        bq, bk, bv, Qp, Kp, Vtp);
    attn_flash<<<dim3(512), bb, 0, stream>>>(Qp, Kp, Vtp, AO);
    gemm_out<<<dim3(MTOT / 128, EMBED / 64), bb, 0, stream>>>(
        AO, Wb + 3 * WSZ, bo, (float*)d_out);
}